// Round 1
// baseline (1039.201 us; speedup 1.0000x reference)
//
#include <hip/hip_runtime.h>
#include <hip/hip_bf16.h>

#define B_  2
#define S_  2048
#define D_  2048
#define H_  16
#define HD_ 128
#define FF_ 8192

typedef __bf16 bf16x8 __attribute__((ext_vector_type(8)));
typedef float  f32x4  __attribute__((ext_vector_type(4)));
typedef unsigned short u16;
typedef u16 u16x8 __attribute__((ext_vector_type(8)));

__device__ __forceinline__ u16 f2bf(float f) {
    union { float f; unsigned u; } c; c.f = f;
    unsigned u = c.u;
    u += 0x7fffu + ((u >> 16) & 1u);   // RNE
    return (u16)(u >> 16);
}

__device__ __forceinline__ void gld16(void* lds, const void* g) {
    __builtin_amdgcn_global_load_lds(
        (const __attribute__((address_space(1))) unsigned int*)g,
        (__attribute__((address_space(3))) unsigned int*)lds,
        16, 0, 0);
}

// ---------------------------------------------------------------- LayerNorm
__global__ __launch_bounds__(256)
void ln_kernel(const float* __restrict__ x, const float* __restrict__ g,
               const float* __restrict__ bb, u16* __restrict__ out)
{
    int row = blockIdx.x, tid = threadIdx.x;
    const float4* xr = (const float4*)(x + (size_t)row * D_);
    float4 a = xr[tid], c = xr[tid + 256];
    float s  = a.x + a.y + a.z + a.w + c.x + c.y + c.z + c.w;
    float s2 = a.x*a.x + a.y*a.y + a.z*a.z + a.w*a.w
             + c.x*c.x + c.y*c.y + c.z*c.z + c.w*c.w;
    #pragma unroll
    for (int off = 32; off > 0; off >>= 1) {
        s  += __shfl_down(s,  off, 64);
        s2 += __shfl_down(s2, off, 64);
    }
    __shared__ float red[16];
    __shared__ float mr[2];
    int wid = tid >> 6, lane = tid & 63;
    if (lane == 0) { red[wid] = s; red[8 + wid] = s2; }
    __syncthreads();
    if (tid == 0) {
        float ts = red[0] + red[1] + red[2] + red[3];
        float t2 = red[8] + red[9] + red[10] + red[11];
        float mu = ts * (1.0f / D_);
        float var = t2 * (1.0f / D_) - mu * mu;
        mr[0] = mu; mr[1] = rsqrtf(var + 1e-5f);
    }
    __syncthreads();
    float mu = mr[0], rstd = mr[1];
    const float4* gg = (const float4*)g;
    const float4* bv = (const float4*)bb;
    float4 g0 = gg[tid], g1 = gg[tid + 256];
    float4 b0 = bv[tid], b1 = bv[tid + 256];
    u16* orow = out + (size_t)row * D_;
    ushort4 o0, o1;
    o0.x = f2bf((a.x - mu) * rstd * g0.x + b0.x);
    o0.y = f2bf((a.y - mu) * rstd * g0.y + b0.y);
    o0.z = f2bf((a.z - mu) * rstd * g0.z + b0.z);
    o0.w = f2bf((a.w - mu) * rstd * g0.w + b0.w);
    o1.x = f2bf((c.x - mu) * rstd * g1.x + b1.x);
    o1.y = f2bf((c.y - mu) * rstd * g1.y + b1.y);
    o1.z = f2bf((c.z - mu) * rstd * g1.z + b1.z);
    o1.w = f2bf((c.w - mu) * rstd * g1.w + b1.w);
    *(ushort4*)&orow[tid * 4]         = o0;
    *(ushort4*)&orow[(tid + 256) * 4] = o1;
}

// ----------------------------------------------- transpose + fp32->bf16 cast
__global__ __launch_bounds__(256)
void tcvt_kernel(const float* __restrict__ W, u16* __restrict__ WT, int K, int N)
{
    __shared__ float t[32][33];
    int n0 = blockIdx.x << 5, k0 = blockIdx.y << 5;
    int tx = threadIdx.x & 31, ty = threadIdx.x >> 5;
    #pragma unroll
    for (int i = 0; i < 32; i += 8)
        t[ty + i][tx] = W[(size_t)(k0 + ty + i) * N + n0 + tx];
    __syncthreads();
    #pragma unroll
    for (int i = 0; i < 32; i += 8)
        WT[(size_t)(n0 + ty + i) * K + k0 + tx] = f2bf(t[tx][ty + i]);
}

// ---------------------------------------------------------------- GEMM bf16
// C[M,N] = A[M,K](bf16,row) * BT[N,K](bf16,row)^T + bias
// 128x256 tile, BK=64, 8 waves (2Mx4N), 8-phase schedule with counted vmcnt:
// LDS = 8 k-sliced slots (A:128x32, B:256x32), XOR-swizzled (2-way max -> free),
// one half-tile restaged per phase, vmcnt(3) only at phases 4/8 (never 0),
// raw s_barrier (no __syncthreads drain), setprio around MFMA cluster.
// Grid: N-major tiles + XCD swizzle (nwg % 8 == 0): each XCD owns whole
// N-columns -> B panel (<=4.2MB) L2-resident, A re-reads from L3.
template<int EPI>
__global__ __launch_bounds__(512, 2)
void gemm_kernel(const u16* __restrict__ A, const u16* __restrict__ BT,
                 const float* __restrict__ bias, const float* __restrict__ res,
                 void* __restrict__ outv, int M, int N, int K)
{
    __shared__ u16 ldsA[4 * 4096];   // 4 slots x (128 rows x 32 k) = 32 KB
    __shared__ u16 ldsB[4 * 8192];   // 4 slots x (256 rows x 32 k) = 64 KB
    (void)M;

    int tid = threadIdx.x;
    int wid = tid >> 6, lane = tid & 63;
    int wm = wid >> 2, wn = wid & 3;          // 2 x 4 wave grid
    int quad = lane >> 4, l16 = lane & 15;

    // XCD-aware bijective swizzle (all grids % 8 == 0), N-major tile order.
    int nwg = (int)gridDim.x;
    int swz = ((int)blockIdx.x & 7) * (nwg >> 3) + ((int)blockIdx.x >> 3);
    int mt = swz & 31;                        // M/128 == 32 for all GEMMs here
    int nt = swz >> 5;
    int m0 = mt << 7, n0 = nt << 8;

    // staging decode: phys slot P = tid -> logical (row, 8-elem chunk), XOR swz
    int lo3 = (tid & 7) ^ ((tid >> 3) & 7);
    int rS  = ((tid >> 3) << 1) | (lo3 >> 2);
    int cS  = (lo3 & 3) << 3;
    const u16* gA  = A  + (size_t)(m0 + rS) * K + cS;
    const u16* gB0 = BT + (size_t)(n0 + rS) * K + cS;
    const u16* gB1 = gB0 + (size_t)128 * K;

    // fragment-read lane offset (u16 units): row=R0+l16, chunk=quad
    int slot   = (((l16 & 1) << 2) | quad) ^ (l16 >> 1);
    int laneRd = (l16 >> 1) * 64 + slot * 8;
    int aRd = wm * 2048 + laneRd;             // wave A rows: wm*64
    int bRd = wn * 2048 + laneRd;             // wave B cols: wn*64

    f32x4 acc[4][4] = {};
    bf16x8 af[4];

    auto stA = [&](int b, int ks, int kofs) {
        gld16(ldsA + (b * 2 + ks) * 4096 + wid * 512, gA + kofs);
    };
    auto stB = [&](int b, int ks, int kofs) {
        gld16(ldsB + (b * 2 + ks) * 8192 + wid * 512, gB0 + kofs);
        gld16(ldsB + (b * 2 + ks) * 8192 + 4096 + wid * 512, gB1 + kofs);
    };
    auto phase = [&](int buf, int ks, int nh, bool ar,
                     bool stb, int sb, int sk, int kofs, bool vm) {
        if (ar) {
            #pragma unroll
            for (int t = 0; t < 4; t++)
                af[t] = *(const bf16x8*)(ldsA + (buf * 2 + ks) * 4096 + aRd + t * 512);
        }
        const u16* bp = ldsB + (buf * 2 + ks) * 8192 + bRd + nh * 1024;
        bf16x8 bf0 = *(const bf16x8*)bp;
        bf16x8 bf1 = *(const bf16x8*)(bp + 512);
        if (!stb) stA(sb, sk, kofs); else stB(sb, sk, kofs);
        if (vm) asm volatile("s_waitcnt vmcnt(3)" ::: "memory");
        __builtin_amdgcn_s_barrier();
        asm volatile("s_waitcnt lgkmcnt(0)" ::: "memory");
        __builtin_amdgcn_sched_barrier(0);
        __builtin_amdgcn_s_setprio(1);
        #pragma unroll
        for (int i = 0; i < 4; i++) {
            acc[i][nh * 2 + 0] = __builtin_amdgcn_mfma_f32_16x16x32_bf16(af[i], bf0, acc[i][nh * 2 + 0], 0, 0, 0);
            acc[i][nh * 2 + 1] = __builtin_amdgcn_mfma_f32_16x16x32_bf16(af[i], bf1, acc[i][nh * 2 + 1], 0, 0, 0);
        }
        __builtin_amdgcn_s_setprio(0);
        __builtin_amdgcn_s_barrier();
    };

    int nkt = K >> 6;
    // prologue: X(=tile0) full + Y(=tile1) k0; leave Y.k0 (3 loads) in flight
    stA(0, 0, 0);  stB(0, 0, 0);
    stA(0, 1, 32); stB(0, 1, 32);
    stA(1, 0, 64); stB(1, 0, 64);
    asm volatile("s_waitcnt vmcnt(3)" ::: "memory");
    __builtin_amdgcn_s_barrier();

    int niter = nkt >> 1;
    for (int it = 0; it < niter; ++it) {
        int t = it << 1;
        int k1 = ((t + 1) << 6) + 32;
        int t2 = t + 2; if (t2 > nkt - 1) t2 = nkt - 1;   // clamped prefetch
        int t3 = t + 3; if (t3 > nkt - 1) t3 = nkt - 1;   // (never consumed)
        int k2 = t2 << 6, k3 = t3 << 6;
        // slot freshness: each slot staged >=1 barrier after its last read;
        // vmcnt(3)@ph4 covers Y.k0 (prev ph7/8) + Y.k1 (ph1/2) for ph5-8;
        // vmcnt(3)@ph8 covers X'(t+2) full (ph3-6) for next-iter ph1-4.
        phase(0, 0, 0, true,  false, 1, 1, k1,      false);
        phase(0, 0, 1, false, true,  1, 1, k1,      false);
        phase(0, 1, 0, true,  false, 0, 0, k2,      false);
        phase(0, 1, 1, false, true,  0, 0, k2,      true);
        phase(1, 0, 0, true,  false, 0, 1, k2 + 32, false);
        phase(1, 0, 1, false, true,  0, 1, k2 + 32, false);
        phase(1, 1, 0, true,  false, 1, 0, k3,      false);
        phase(1, 1, 1, false, true,  1, 0, k3,      true);
    }

    u16*   outb = (u16*)outv;
    float* outf = (float*)outv;
    int colb = n0 + wn * 64, rowb = m0 + wm * 64;
    #pragma unroll
    for (int j = 0; j < 4; j++) {
        int col = colb + j * 16 + l16;
        float bv = bias[col];
        #pragma unroll
        for (int i = 0; i < 4; i++) {
            int row0 = rowb + i * 16 + (quad << 2);
            #pragma unroll
            for (int r = 0; r < 4; r++) {
                float v = acc[i][j][r] + bv;
                size_t idx = (size_t)(row0 + r) * N + col;
                if (EPI == 2) {
                    outf[idx] = v + res[idx];
                } else {
                    if (EPI == 1) v = 0.5f * v * (1.0f + erff(v * 0.70710678118654752f));
                    outb[idx] = f2bf(v);
                }
            }
        }
    }
}

// ---------------------------------------------------------- flash attention
__global__ __launch_bounds__(256, 2)
void attn_kernel(const u16* __restrict__ qkv, u16* __restrict__ av)
{
    __shared__ u16 ldsK[4][64][32];          // 16 KB  [d-chunk][key][32]
    __shared__ unsigned ldsVT[128][36];      // 18 KB  [d][key-pair]
    __shared__ u16 ldsP[4][32][72];          // 18 KB  per-wave P (2 sets)
    int tid = threadIdx.x, wid = tid >> 6, lane = tid & 63;
    int quad = lane >> 4, l16 = lane & 15;
    int bh = blockIdx.y, b = bh >> 4, h = bh & 15;
    int qx = gridDim.x - 1 - blockIdx.x;     // heavy causal blocks first
    int q0 = qx << 7;
    const u16* base = qkv + (size_t)b * S_ * (3 * D_);

    bf16x8 aq[2][4];
    #pragma unroll
    for (int set = 0; set < 2; set++) {
        int qrow = q0 + set * 64 + wid * 16 + l16;
        const u16* qp = base + (size_t)qrow * (3 * D_) + h * HD_;
        #pragma unroll
        for (int kk = 0; kk < 4; kk++)
            aq[set][kk] = *(const bf16x8*)(qp + kk * 32 + quad * 8);
    }

    float m_i[2][4], l_i[2][4];
    f32x4 oacc[2][8] = {};
    #pragma unroll
    for (int s = 0; s < 2; s++)
        #pragma unroll
        for (int r = 0; r < 4; r++) { m_i[s][r] = -1e30f; l_i[s][r] = 0.f; }

    const float scale = 0.088388347648318447f;  // 1/sqrt(128)
    int ntile = 2 * qx + 2;
    for (int jt = 0; jt < ntile; jt++) {
        int j0 = jt << 6;
        #pragma unroll
        for (int j = 0; j < 4; j++) {
            int c = wid * 4 + j;
            int kk = c >> 2, kb = c & 3;
            int key = (kb << 4) + (lane >> 2);
            const u16* g = base + (size_t)(j0 + key) * (3 * D_) + D_ + h * HD_
                         + kk * 32 + ((lane & 3) << 3);
            gld16((u16*)ldsK + c * 512, g);
        }
        {
            int kp = lane & 31, dhalf = lane >> 5;
            #pragma unroll
            for (int p = 0; p < 2; p++) {
                int doff = wid * 32 + p * 16 + dhalf * 8;
                const u16* g0 = base + (size_t)(j0 + 2 * kp) * (3 * D_)
                              + 2 * D_ + h * HD_ + doff;
                u16x8 v0 = *(const u16x8*)g0;
                u16x8 v1 = *(const u16x8*)(g0 + 3 * D_);
                #pragma unroll
                for (int k = 0; k < 8; k++)
                    ldsVT[doff + k][kp] = (unsigned)v0[k] | ((unsigned)v1[k] << 16);
            }
        }
        __syncthreads();
        f32x4 sacc[2][4] = {};
        #pragma unroll
        for (int kk = 0; kk < 4; kk++)
            #pragma unroll
            for (int n = 0; n < 4; n++) {
                bf16x8 bfr = *(const bf16x8*)&ldsK[kk][(n << 4) + l16][quad << 3];
                sacc[0][n] = __builtin_amdgcn_mfma_f32_16x16x32_bf16(aq[0][kk], bfr, sacc[0][n], 0, 0, 0);
                sacc[1][n] = __builtin_amdgcn_mfma_f32_16x16x32_bf16(aq[1][kk], bfr, sacc[1][n], 0, 0, 0);
            }
        #pragma unroll
        for (int set = 0; set < 2; set++) {
            float rowmax[4] = {-1e30f, -1e30f, -1e30f, -1e30f};
            #pragma unroll
            for (int n = 0; n < 4; n++) {
                int key = j0 + (n << 4) + l16;
                #pragma unroll
                for (int r = 0; r < 4; r++) {
                    float xv = sacc[set][n][r] * scale;
                    int qr = q0 + set * 64 + wid * 16 + (quad << 2) + r;
                    if (key > qr) xv = -1e30f;
                    sacc[set][n][r] = xv;
                    rowmax[r] = fmaxf(rowmax[r], xv);
                }
            }
            #pragma unroll
            for (int off = 1; off < 16; off <<= 1)
                #pragma unroll
                for (int r = 0; r < 4; r++)
                    rowmax[r] = fmaxf(rowmax[r], __shfl_xor(rowmax[r], off, 64));
            float alpha[4], rsum[4];
            #pragma unroll
            for (int r = 0; r < 4; r++) {
                float mn = fmaxf(m_i[set][r], rowmax[r]);
                alpha[r] = __expf(m_i[set][r] - mn);
                m_i[set][r] = mn;
                rsum[r] = 0.f;
            }
            #pragma unroll
            for (int n = 0; n < 4; n++)
                #pragma unroll
                for (int r = 0; r < 4; r++) {
                    float p = __expf(sacc[set][n][r] - m_i[set][r]);
                    rsum[r] += p;
                    ldsP[wid][set * 16 + (quad << 2) + r][(n << 4) + l16] = f2bf(p);
                }
            #pragma unroll
            for (int off = 1; off < 16; off <<= 1)
                #pragma unroll
                for (int r = 0; r < 4; r++)
                    rsum[r] += __shfl_xor(rsum[r], off, 64);
            #pragma unroll
            for (int r = 0; r < 4; r++)
                l_i[set][r] = l_i[set][r] * alpha[r] + rsum[r];
            #pragma unroll
            for (int n = 0; n < 8; n++)
                #pragma unroll
                for (int r = 0; r < 4; r++)
                    oacc[set][n][r] *= alpha[r];
        }
        #pragma unroll
        for (int ks = 0; ks < 2; ks++) {
            bf16x8 pa0 = *(const bf16x8*)&ldsP[wid][l16]     [(ks << 5) + (quad << 3)];
            bf16x8 pa1 = *(const bf16x8*)&ldsP[wid][16 + l16][(ks << 5) + (quad << 3)];
            #pragma unroll
            for (int n = 0; n < 8; n++) {
                bf16x8 vb = *(const bf16x8*)&ldsVT[(n << 4) + l16][(ks << 4) + (quad << 2)];
                oacc[0][n] = __builtin_amdgcn_mfma_f32_16x16x32_bf16(pa0, vb, oacc[0][n], 0, 0, 0);
                oacc[1][n] = __builtin_amdgcn_mfma_f32_16x16x32_bf16(pa1, vb, oacc[1][n], 0, 0, 0);
            }
        }
        __syncthreads();
    }
    #pragma unroll
    for (int set = 0; set < 2; set++)
        #pragma unroll
        for (int r = 0; r < 4; r++) {
            float inv = 1.0f / l_i[set][r];
            int qr = q0 + set * 64 + wid * 16 + (quad << 2) + r;
            u16* op = av + (size_t)(b * S_ + qr) * D_ + h * HD_;
            #pragma unroll
            for (int n = 0; n < 8; n++)
                op[(n << 4) + l16] = f2bf(oacc[set][n][r] * inv);
        }
}

// ------------------------------------------------------------------- launch
extern "C" void kernel_launch(void* const* d_in, const int* in_sizes, int n_in,
                              void* d_out, int out_size, void* d_ws, size_t ws_size,
                              hipStream_t stream)
{
    const float* x     = (const float*)d_in[0];
    const float* ln1_g = (const float*)d_in[1];
    const float* ln1_b = (const float*)d_in[2];
    const float* qkv_w = (const float*)d_in[3];
    const float* qkv_b = (const float*)d_in[4];
    const float* out_w = (const float*)d_in[5];
    const float* out_b = (const float*)d_in[6];
    const float* ln2_g = (const float*)d_in[7];
    const float* ln2_b = (const float*)d_in[8];
    const float* w1    = (const float*)d_in[9];
    const float* b1    = (const float*)d_in[10];
    const float* w2    = (const float*)d_in[11];
    const float* b2    = (const float*)d_in[12];
    float* out = (float*)d_out;

    char* ws  = (char*)d_ws;
    u16* wT   = (u16*)ws;                        // 32 MiB: transposed bf16 weights
    u16* hbuf = (u16*)(ws + (32u << 20));        // 16 MiB: ln1-out / av / ln2-out
    u16* big  = (u16*)(ws + (48u << 20));        // 64 MiB: qkv, then ffn act
    u16* qkvb = big;
    u16* ffb  = big;

    dim3 blk(256);
    dim3 gblk(512);

    ln_kernel<<<dim3(B_ * S_), blk, 0, stream>>>(x, ln1_g, ln1_b, hbuf);
    tcvt_kernel<<<dim3(6144 / 32, 2048 / 32), blk, 0, stream>>>(qkv_w, wT, 2048, 6144);
    gemm_kernel<0><<<dim3((6144 / 256) * (4096 / 128)), gblk, 0, stream>>>(
        hbuf, wT, qkv_b, nullptr, (void*)qkvb, 4096, 6144, 2048);
    attn_kernel<<<dim3(S_ / 128, B_ * H_), blk, 0, stream>>>(qkvb, hbuf);
    tcvt_kernel<<<dim3(2048 / 32, 2048 / 32), blk, 0, stream>>>(out_w, wT, 2048, 2048);
    gemm_kernel<2><<<dim3((2048 / 256) * (4096 / 128)), gblk, 0, stream>>>(
        hbuf, wT, out_b, x, (void*)out, 4096, 2048, 2048);
    ln_kernel<<<dim3(B_ * S_), blk, 0, stream>>>(out, ln2_g, ln2_b, hbuf);
    tcvt_kernel<<<dim3(8192 / 32, 2048 / 32), blk, 0, stream>>>(w1, wT, 2048, 8192);
    gemm_kernel<1><<<dim3((8192 / 256) * (4096 / 128)), gblk, 0, stream>>>(
        hbuf, wT, b1, nullptr, (void*)ffb, 4096, 8192, 2048);
    tcvt_kernel<<<dim3(2048 / 32, 8192 / 32), blk, 0, stream>>>(w2, wT, 8192, 2048);
    gemm_kernel<2><<<dim3((2048 / 256) * (4096 / 128)), gblk, 0, stream>>>(
        ffb, wT, b2, out, (void*)out, 4096, 2048, 8192);
}

// Round 2
// 943.500 us; speedup vs baseline: 1.1014x; 1.1014x over previous
//
#include <hip/hip_runtime.h>
#include <hip/hip_bf16.h>

#define B_  2
#define S_  2048
#define D_  2048
#define H_  16
#define HD_ 128
#define FF_ 8192

typedef __bf16 bf16x8 __attribute__((ext_vector_type(8)));
typedef float  f32x4  __attribute__((ext_vector_type(4)));
typedef unsigned short u16;
typedef u16 u16x8 __attribute__((ext_vector_type(8)));

__device__ __forceinline__ u16 f2bf(float f) {
    union { float f; unsigned u; } c; c.f = f;
    unsigned u = c.u;
    u += 0x7fffu + ((u >> 16) & 1u);   // RNE
    return (u16)(u >> 16);
}

__device__ __forceinline__ void gld16(void* lds, const void* g) {
    __builtin_amdgcn_global_load_lds(
        (const __attribute__((address_space(1))) unsigned int*)g,
        (__attribute__((address_space(3))) unsigned int*)lds,
        16, 0, 0);
}

// ---------------------------------------------------------------- LayerNorm
__global__ __launch_bounds__(256)
void ln_kernel(const float* __restrict__ x, const float* __restrict__ g,
               const float* __restrict__ bb, u16* __restrict__ out)
{
    int row = blockIdx.x, tid = threadIdx.x;
    const float4* xr = (const float4*)(x + (size_t)row * D_);
    float4 a = xr[tid], c = xr[tid + 256];
    float s  = a.x + a.y + a.z + a.w + c.x + c.y + c.z + c.w;
    float s2 = a.x*a.x + a.y*a.y + a.z*a.z + a.w*a.w
             + c.x*c.x + c.y*c.y + c.z*c.z + c.w*c.w;
    #pragma unroll
    for (int off = 32; off > 0; off >>= 1) {
        s  += __shfl_down(s,  off, 64);
        s2 += __shfl_down(s2, off, 64);
    }
    __shared__ float red[16];
    __shared__ float mr[2];
    int wid = tid >> 6, lane = tid & 63;
    if (lane == 0) { red[wid] = s; red[8 + wid] = s2; }
    __syncthreads();
    if (tid == 0) {
        float ts = red[0] + red[1] + red[2] + red[3];
        float t2 = red[8] + red[9] + red[10] + red[11];
        float mu = ts * (1.0f / D_);
        float var = t2 * (1.0f / D_) - mu * mu;
        mr[0] = mu; mr[1] = rsqrtf(var + 1e-5f);
    }
    __syncthreads();
    float mu = mr[0], rstd = mr[1];
    const float4* gg = (const float4*)g;
    const float4* bv = (const float4*)bb;
    float4 g0 = gg[tid], g1 = gg[tid + 256];
    float4 b0 = bv[tid], b1 = bv[tid + 256];
    u16* orow = out + (size_t)row * D_;
    ushort4 o0, o1;
    o0.x = f2bf((a.x - mu) * rstd * g0.x + b0.x);
    o0.y = f2bf((a.y - mu) * rstd * g0.y + b0.y);
    o0.z = f2bf((a.z - mu) * rstd * g0.z + b0.z);
    o0.w = f2bf((a.w - mu) * rstd * g0.w + b0.w);
    o1.x = f2bf((c.x - mu) * rstd * g1.x + b1.x);
    o1.y = f2bf((c.y - mu) * rstd * g1.y + b1.y);
    o1.z = f2bf((c.z - mu) * rstd * g1.z + b1.z);
    o1.w = f2bf((c.w - mu) * rstd * g1.w + b1.w);
    *(ushort4*)&orow[tid * 4]         = o0;
    *(ushort4*)&orow[(tid + 256) * 4] = o1;
}

// ----------------------------------------------- transpose + fp32->bf16 cast
__global__ __launch_bounds__(256)
void tcvt_kernel(const float* __restrict__ W, u16* __restrict__ WT, int K, int N)
{
    __shared__ float t[32][33];
    int n0 = blockIdx.x << 5, k0 = blockIdx.y << 5;
    int tx = threadIdx.x & 31, ty = threadIdx.x >> 5;
    #pragma unroll
    for (int i = 0; i < 32; i += 8)
        t[ty + i][tx] = W[(size_t)(k0 + ty + i) * N + n0 + tx];
    __syncthreads();
    #pragma unroll
    for (int i = 0; i < 32; i += 8)
        WT[(size_t)(n0 + ty + i) * K + k0 + tx] = f2bf(t[tx][ty + i]);
}

// ---------------------------------------------------------------- GEMM bf16
// C[M,N] = A[M,K](bf16,row) * BT[N,K](bf16,row)^T + bias
// 128x256 tile, BK=64, 8 waves (2Mx4N). Triple-buffered K-tiles (144 KB LDS):
// tile t+2 staged while computing tile t -> ~4 phases of load lead.
// 2 phases per K-tile, 16 independent MFMA per phase between raw s_barriers.
// Single vmcnt(6) per K-tile (one tile's 6 loads stay in flight, never 0).
// Grid: N-major tiles + XCD swizzle (nwg % 8 == 0).
template<int EPI>
__global__ __launch_bounds__(512, 2)
void gemm_kernel(const u16* __restrict__ A, const u16* __restrict__ BT,
                 const float* __restrict__ bias, const float* __restrict__ res,
                 void* __restrict__ outv, int M, int N, int K)
{
    __shared__ u16 ldsA[3 * 8192];   // 3 bufs x 2 kslices x (128 x 32) = 48 KB
    __shared__ u16 ldsB[3 * 16384];  // 3 bufs x 2 kslices x (256 x 32) = 96 KB
    (void)M;

    int tid = threadIdx.x;
    int wid = tid >> 6, lane = tid & 63;
    int wm = wid >> 2, wn = wid & 3;          // 2 x 4 wave grid
    int quad = lane >> 4, l16 = lane & 15;

    // XCD-aware bijective swizzle (all grids % 8 == 0), N-major tile order.
    int nwg = (int)gridDim.x;
    int swz = ((int)blockIdx.x & 7) * (nwg >> 3) + ((int)blockIdx.x >> 3);
    int mt = swz & 31;                        // M/128 == 32 for all GEMMs here
    int nt = swz >> 5;
    int m0 = mt << 7, n0 = nt << 8;

    // staging decode: phys slot P = tid -> logical (row, 8-elem chunk), XOR swz
    int lo3 = (tid & 7) ^ ((tid >> 3) & 7);
    int rS  = ((tid >> 3) << 1) | (lo3 >> 2);
    int cS  = (lo3 & 3) << 3;
    const u16* gA  = A  + (size_t)(m0 + rS) * K + cS;
    const u16* gB0 = BT + (size_t)(n0 + rS) * K + cS;
    const u16* gB1 = gB0 + (size_t)128 * K;

    // fragment-read lane offset (u16 units): row=R0+l16, chunk=quad
    int slot   = (((l16 & 1) << 2) | quad) ^ (l16 >> 1);
    int laneRd = (l16 >> 1) * 64 + slot * 8;
    int aRd = wm * 2048 + laneRd;             // wave A rows: wm*64
    int bRd = wn * 2048 + laneRd;             // wave B cols: wn*64

    f32x4 acc[4][4] = {};

    auto stA = [&](int b, int ks, int kofs) {
        gld16(ldsA + b * 8192 + ks * 4096 + wid * 512, gA + kofs);
    };
    auto stB = [&](int b, int ks, int kofs) {
        gld16(ldsB + b * 16384 + ks * 8192 + wid * 512, gB0 + kofs);
        gld16(ldsB + b * 16384 + ks * 8192 + 4096 + wid * 512, gB1 + kofs);
    };
    // one phase = one k-step: 8 ds_read_b128, 3 gld16, 16 independent MFMA
    auto phase = [&](int bt, int ks, int stg, int kofs, bool vm) {
        const u16* ap = ldsA + bt * 8192 + ks * 4096 + aRd;
        bf16x8 af0 = *(const bf16x8*)(ap);
        bf16x8 af1 = *(const bf16x8*)(ap + 512);
        bf16x8 af2 = *(const bf16x8*)(ap + 1024);
        bf16x8 af3 = *(const bf16x8*)(ap + 1536);
        const u16* bp = ldsB + bt * 16384 + ks * 8192 + bRd;
        bf16x8 bf0 = *(const bf16x8*)(bp);
        bf16x8 bf1 = *(const bf16x8*)(bp + 512);
        bf16x8 bf2 = *(const bf16x8*)(bp + 1024);
        bf16x8 bf3 = *(const bf16x8*)(bp + 1536);
        stA(stg, ks, kofs);
        stB(stg, ks, kofs);
        __builtin_amdgcn_s_barrier();
        asm volatile("s_waitcnt lgkmcnt(0)" ::: "memory");
        __builtin_amdgcn_sched_barrier(0);
        __builtin_amdgcn_s_setprio(1);
        acc[0][0] = __builtin_amdgcn_mfma_f32_16x16x32_bf16(af0, bf0, acc[0][0], 0, 0, 0);
        acc[0][1] = __builtin_amdgcn_mfma_f32_16x16x32_bf16(af0, bf1, acc[0][1], 0, 0, 0);
        acc[0][2] = __builtin_amdgcn_mfma_f32_16x16x32_bf16(af0, bf2, acc[0][2], 0, 0, 0);
        acc[0][3] = __builtin_amdgcn_mfma_f32_16x16x32_bf16(af0, bf3, acc[0][3], 0, 0, 0);
        acc[1][0] = __builtin_amdgcn_mfma_f32_16x16x32_bf16(af1, bf0, acc[1][0], 0, 0, 0);
        acc[1][1] = __builtin_amdgcn_mfma_f32_16x16x32_bf16(af1, bf1, acc[1][1], 0, 0, 0);
        acc[1][2] = __builtin_amdgcn_mfma_f32_16x16x32_bf16(af1, bf2, acc[1][2], 0, 0, 0);
        acc[1][3] = __builtin_amdgcn_mfma_f32_16x16x32_bf16(af1, bf3, acc[1][3], 0, 0, 0);
        acc[2][0] = __builtin_amdgcn_mfma_f32_16x16x32_bf16(af2, bf0, acc[2][0], 0, 0, 0);
        acc[2][1] = __builtin_amdgcn_mfma_f32_16x16x32_bf16(af2, bf1, acc[2][1], 0, 0, 0);
        acc[2][2] = __builtin_amdgcn_mfma_f32_16x16x32_bf16(af2, bf2, acc[2][2], 0, 0, 0);
        acc[2][3] = __builtin_amdgcn_mfma_f32_16x16x32_bf16(af2, bf3, acc[2][3], 0, 0, 0);
        acc[3][0] = __builtin_amdgcn_mfma_f32_16x16x32_bf16(af3, bf0, acc[3][0], 0, 0, 0);
        acc[3][1] = __builtin_amdgcn_mfma_f32_16x16x32_bf16(af3, bf1, acc[3][1], 0, 0, 0);
        acc[3][2] = __builtin_amdgcn_mfma_f32_16x16x32_bf16(af3, bf2, acc[3][2], 0, 0, 0);
        acc[3][3] = __builtin_amdgcn_mfma_f32_16x16x32_bf16(af3, bf3, acc[3][3], 0, 0, 0);
        __builtin_amdgcn_s_setprio(0);
        if (vm) asm volatile("s_waitcnt vmcnt(6)" ::: "memory");
        __builtin_amdgcn_s_barrier();
    };

    int nkt = K >> 6;
    // prologue: stage T0, T1 fully; T0 landed (T1's 6 may stay in flight)
    stA(0, 0, 0);  stB(0, 0, 0);
    stA(0, 1, 32); stB(0, 1, 32);
    stA(1, 0, 64); stB(1, 0, 64);
    stA(1, 1, 96); stB(1, 1, 96);
    asm volatile("s_waitcnt vmcnt(6)" ::: "memory");
    __builtin_amdgcn_s_barrier();

    int cur = 0;
    for (int t = 0; t < nkt; ++t) {
        int stg = cur - 1; if (stg < 0) stg = 2;       // (cur + 2) % 3
        int tp = t + 2; if (tp > nkt - 1) tp = nkt - 1; // clamped (dead slot)
        int kofs = tp << 6;
        phase(cur, 0, stg, kofs,      false);
        phase(cur, 1, stg, kofs + 32, true);   // vmcnt(6): T(t+1) landed
        cur = cur + 1; if (cur > 2) cur = 0;
    }
    asm volatile("s_waitcnt vmcnt(0)" ::: "memory"); // drain LDS-DMA pre-endpgm

    u16*   outb = (u16*)outv;
    float* outf = (float*)outv;
    int colb = n0 + wn * 64, rowb = m0 + wm * 64;
    #pragma unroll
    for (int j = 0; j < 4; j++) {
        int col = colb + j * 16 + l16;
        float bv = bias[col];
        #pragma unroll
        for (int i = 0; i < 4; i++) {
            int row0 = rowb + i * 16 + (quad << 2);
            #pragma unroll
            for (int r = 0; r < 4; r++) {
                float v = acc[i][j][r] + bv;
                size_t idx = (size_t)(row0 + r) * N + col;
                if (EPI == 2) {
                    outf[idx] = v + res[idx];
                } else {
                    if (EPI == 1) v = 0.5f * v * (1.0f + erff(v * 0.70710678118654752f));
                    outb[idx] = f2bf(v);
                }
            }
        }
    }
}

// ---------------------------------------------------------- flash attention
__global__ __launch_bounds__(256, 2)
void attn_kernel(const u16* __restrict__ qkv, u16* __restrict__ av)
{
    __shared__ u16 ldsK[4][64][32];          // 16 KB  [d-chunk][key][32]
    __shared__ unsigned ldsVT[128][36];      // 18 KB  [d][key-pair]
    __shared__ u16 ldsP[4][32][72];          // 18 KB  per-wave P (2 sets)
    int tid = threadIdx.x, wid = tid >> 6, lane = tid & 63;
    int quad = lane >> 4, l16 = lane & 15;
    int bh = blockIdx.y, b = bh >> 4, h = bh & 15;
    int qx = gridDim.x - 1 - blockIdx.x;     // heavy causal blocks first
    int q0 = qx << 7;
    const u16* base = qkv + (size_t)b * S_ * (3 * D_);

    bf16x8 aq[2][4];
    #pragma unroll
    for (int set = 0; set < 2; set++) {
        int qrow = q0 + set * 64 + wid * 16 + l16;
        const u16* qp = base + (size_t)qrow * (3 * D_) + h * HD_;
        #pragma unroll
        for (int kk = 0; kk < 4; kk++)
            aq[set][kk] = *(const bf16x8*)(qp + kk * 32 + quad * 8);
    }

    float m_i[2][4], l_i[2][4];
    f32x4 oacc[2][8] = {};
    #pragma unroll
    for (int s = 0; s < 2; s++)
        #pragma unroll
        for (int r = 0; r < 4; r++) { m_i[s][r] = -1e30f; l_i[s][r] = 0.f; }

    const float scale = 0.088388347648318447f;  // 1/sqrt(128)
    int ntile = 2 * qx + 2;
    for (int jt = 0; jt < ntile; jt++) {
        int j0 = jt << 6;
        #pragma unroll
        for (int j = 0; j < 4; j++) {
            int c = wid * 4 + j;
            int kk = c >> 2, kb = c & 3;
            int key = (kb << 4) + (lane >> 2);
            const u16* g = base + (size_t)(j0 + key) * (3 * D_) + D_ + h * HD_
                         + kk * 32 + ((lane & 3) << 3);
            gld16((u16*)ldsK + c * 512, g);
        }
        {
            int kp = lane & 31, dhalf = lane >> 5;
            #pragma unroll
            for (int p = 0; p < 2; p++) {
                int doff = wid * 32 + p * 16 + dhalf * 8;
                const u16* g0 = base + (size_t)(j0 + 2 * kp) * (3 * D_)
                              + 2 * D_ + h * HD_ + doff;
                u16x8 v0 = *(const u16x8*)g0;
                u16x8 v1 = *(const u16x8*)(g0 + 3 * D_);
                #pragma unroll
                for (int k = 0; k < 8; k++)
                    ldsVT[doff + k][kp] = (unsigned)v0[k] | ((unsigned)v1[k] << 16);
            }
        }
        __syncthreads();
        f32x4 sacc[2][4] = {};
        #pragma unroll
        for (int kk = 0; kk < 4; kk++)
            #pragma unroll
            for (int n = 0; n < 4; n++) {
                bf16x8 bfr = *(const bf16x8*)&ldsK[kk][(n << 4) + l16][quad << 3];
                sacc[0][n] = __builtin_amdgcn_mfma_f32_16x16x32_bf16(aq[0][kk], bfr, sacc[0][n], 0, 0, 0);
                sacc[1][n] = __builtin_amdgcn_mfma_f32_16x16x32_bf16(aq[1][kk], bfr, sacc[1][n], 0, 0, 0);
            }
        #pragma unroll
        for (int set = 0; set < 2; set++) {
            float rowmax[4] = {-1e30f, -1e30f, -1e30f, -1e30f};
            #pragma unroll
            for (int n = 0; n < 4; n++) {
                int key = j0 + (n << 4) + l16;
                #pragma unroll
                for (int r = 0; r < 4; r++) {
                    float xv = sacc[set][n][r] * scale;
                    int qr = q0 + set * 64 + wid * 16 + (quad << 2) + r;
                    if (key > qr) xv = -1e30f;
                    sacc[set][n][r] = xv;
                    rowmax[r] = fmaxf(rowmax[r], xv);
                }
            }
            #pragma unroll
            for (int off = 1; off < 16; off <<= 1)
                #pragma unroll
                for (int r = 0; r < 4; r++)
                    rowmax[r] = fmaxf(rowmax[r], __shfl_xor(rowmax[r], off, 64));
            float alpha[4], rsum[4];
            #pragma unroll
            for (int r = 0; r < 4; r++) {
                float mn = fmaxf(m_i[set][r], rowmax[r]);
                alpha[r] = __expf(m_i[set][r] - mn);
                m_i[set][r] = mn;
                rsum[r] = 0.f;
            }
            #pragma unroll
            for (int n = 0; n < 4; n++)
                #pragma unroll
                for (int r = 0; r < 4; r++) {
                    float p = __expf(sacc[set][n][r] - m_i[set][r]);
                    rsum[r] += p;
                    ldsP[wid][set * 16 + (quad << 2) + r][(n << 4) + l16] = f2bf(p);
                }
            #pragma unroll
            for (int off = 1; off < 16; off <<= 1)
                #pragma unroll
                for (int r = 0; r < 4; r++)
                    rsum[r] += __shfl_xor(rsum[r], off, 64);
            #pragma unroll
            for (int r = 0; r < 4; r++)
                l_i[set][r] = l_i[set][r] * alpha[r] + rsum[r];
            #pragma unroll
            for (int n = 0; n < 8; n++)
                #pragma unroll
                for (int r = 0; r < 4; r++)
                    oacc[set][n][r] *= alpha[r];
        }
        #pragma unroll
        for (int ks = 0; ks < 2; ks++) {
            bf16x8 pa0 = *(const bf16x8*)&ldsP[wid][l16]     [(ks << 5) + (quad << 3)];
            bf16x8 pa1 = *(const bf16x8*)&ldsP[wid][16 + l16][(ks << 5) + (quad << 3)];
            #pragma unroll
            for (int n = 0; n < 8; n++) {
                bf16x8 vb = *(const bf16x8*)&ldsVT[(n << 4) + l16][(ks << 4) + (quad << 2)];
                oacc[0][n] = __builtin_amdgcn_mfma_f32_16x16x32_bf16(pa0, vb, oacc[0][n], 0, 0, 0);
                oacc[1][n] = __builtin_amdgcn_mfma_f32_16x16x32_bf16(pa1, vb, oacc[1][n], 0, 0, 0);
            }
        }
        __syncthreads();
    }
    #pragma unroll
    for (int set = 0; set < 2; set++)
        #pragma unroll
        for (int r = 0; r < 4; r++) {
            float inv = 1.0f / l_i[set][r];
            int qr = q0 + set * 64 + wid * 16 + (quad << 2) + r;
            u16* op = av + (size_t)(b * S_ + qr) * D_ + h * HD_;
            #pragma unroll
            for (int n = 0; n < 8; n++)
                op[(n << 4) + l16] = f2bf(oacc[set][n][r] * inv);
        }
}

// ------------------------------------------------------------------- launch
extern "C" void kernel_launch(void* const* d_in, const int* in_sizes, int n_in,
                              void* d_out, int out_size, void* d_ws, size_t ws_size,
                              hipStream_t stream)
{
    const float* x     = (const float*)d_in[0];
    const float* ln1_g = (const float*)d_in[1];
    const float* ln1_b = (const float*)d_in[2];
    const float* qkv_w = (const float*)d_in[3];
    const float* qkv_b = (const float*)d_in[4];
    const float* out_w = (const float*)d_in[5];
    const float* out_b = (const float*)d_in[6];
    const float* ln2_g = (const float*)d_in[7];
    const float* ln2_b = (const float*)d_in[8];
    const float* w1    = (const float*)d_in[9];
    const float* b1    = (const float*)d_in[10];
    const float* w2    = (const float*)d_in[11];
    const float* b2    = (const float*)d_in[12];
    float* out = (float*)d_out;

    char* ws  = (char*)d_ws;
    u16* wT   = (u16*)ws;                        // 32 MiB: transposed bf16 weights
    u16* hbuf = (u16*)(ws + (32u << 20));        // 16 MiB: ln1-out / av / ln2-out
    u16* big  = (u16*)(ws + (48u << 20));        // 64 MiB: qkv, then ffn act
    u16* qkvb = big;
    u16* ffb  = big;

    dim3 blk(256);
    dim3 gblk(512);

    ln_kernel<<<dim3(B_ * S_), blk, 0, stream>>>(x, ln1_g, ln1_b, hbuf);
    tcvt_kernel<<<dim3(6144 / 32, 2048 / 32), blk, 0, stream>>>(qkv_w, wT, 2048, 6144);
    gemm_kernel<0><<<dim3((6144 / 256) * (4096 / 128)), gblk, 0, stream>>>(
        hbuf, wT, qkv_b, nullptr, (void*)qkvb, 4096, 6144, 2048);
    attn_kernel<<<dim3(S_ / 128, B_ * H_), blk, 0, stream>>>(qkvb, hbuf);
    tcvt_kernel<<<dim3(2048 / 32, 2048 / 32), blk, 0, stream>>>(out_w, wT, 2048, 2048);
    gemm_kernel<2><<<dim3((2048 / 256) * (4096 / 128)), gblk, 0, stream>>>(
        hbuf, wT, out_b, x, (void*)out, 4096, 2048, 2048);
    ln_kernel<<<dim3(B_ * S_), blk, 0, stream>>>(out, ln2_g, ln2_b, hbuf);
    tcvt_kernel<<<dim3(8192 / 32, 2048 / 32), blk, 0, stream>>>(w1, wT, 2048, 8192);
    gemm_kernel<1><<<dim3((8192 / 256) * (4096 / 128)), gblk, 0, stream>>>(
        hbuf, wT, b1, nullptr, (void*)ffb, 4096, 8192, 2048);
    tcvt_kernel<<<dim3(2048 / 32, 8192 / 32), blk, 0, stream>>>(w2, wT, 8192, 2048);
    gemm_kernel<2><<<dim3((2048 / 256) * (4096 / 128)), gblk, 0, stream>>>(
        ffb, wT, b2, out, (void*)out, 4096, 2048, 8192);
}

// Round 3
// 928.950 us; speedup vs baseline: 1.1187x; 1.0157x over previous
//
#include <hip/hip_runtime.h>
#include <hip/hip_bf16.h>

#define B_  2
#define S_  2048
#define D_  2048
#define H_  16
#define HD_ 128
#define FF_ 8192

typedef __bf16 bf16x8 __attribute__((ext_vector_type(8)));
typedef float  f32x4  __attribute__((ext_vector_type(4)));
typedef unsigned short u16;
typedef u16 u16x8 __attribute__((ext_vector_type(8)));
typedef unsigned uv4 __attribute__((ext_vector_type(4)));

__device__ __forceinline__ u16 f2bf(float f) {
    union { float f; unsigned u; } c; c.f = f;
    unsigned u = c.u;
    u += 0x7fffu + ((u >> 16) & 1u);   // RNE
    return (u16)(u >> 16);
}

__device__ __forceinline__ void gld16(void* lds, const void* g) {
    __builtin_amdgcn_global_load_lds(
        (const __attribute__((address_space(1))) unsigned int*)g,
        (__attribute__((address_space(3))) unsigned int*)lds,
        16, 0, 0);
}

// inline-asm LDS read: opaque to the waitcnt pass -> no compiler-inserted
// vmcnt(0) alias-drain against outstanding global_load_lds (rule #18).
__device__ __forceinline__ bf16x8 dsr16(const u16* p) {
    unsigned a = (unsigned)(unsigned long long)
                 (const __attribute__((address_space(3))) u16*)p;
    uv4 r;
    asm volatile("ds_read_b128 %0, %1" : "=v"(r) : "v"(a));
    union { uv4 u; bf16x8 b; } c; c.u = r;
    return c.b;
}

// ---------------------------------------------------------------- LayerNorm
__global__ __launch_bounds__(256)
void ln_kernel(const float* __restrict__ x, const float* __restrict__ g,
               const float* __restrict__ bb, u16* __restrict__ out)
{
    int row = blockIdx.x, tid = threadIdx.x;
    const float4* xr = (const float4*)(x + (size_t)row * D_);
    float4 a = xr[tid], c = xr[tid + 256];
    float s  = a.x + a.y + a.z + a.w + c.x + c.y + c.z + c.w;
    float s2 = a.x*a.x + a.y*a.y + a.z*a.z + a.w*a.w
             + c.x*c.x + c.y*c.y + c.z*c.z + c.w*c.w;
    #pragma unroll
    for (int off = 32; off > 0; off >>= 1) {
        s  += __shfl_down(s,  off, 64);
        s2 += __shfl_down(s2, off, 64);
    }
    __shared__ float red[16];
    __shared__ float mr[2];
    int wid = tid >> 6, lane = tid & 63;
    if (lane == 0) { red[wid] = s; red[8 + wid] = s2; }
    __syncthreads();
    if (tid == 0) {
        float ts = red[0] + red[1] + red[2] + red[3];
        float t2 = red[8] + red[9] + red[10] + red[11];
        float mu = ts * (1.0f / D_);
        float var = t2 * (1.0f / D_) - mu * mu;
        mr[0] = mu; mr[1] = rsqrtf(var + 1e-5f);
    }
    __syncthreads();
    float mu = mr[0], rstd = mr[1];
    const float4* gg = (const float4*)g;
    const float4* bv = (const float4*)bb;
    float4 g0 = gg[tid], g1 = gg[tid + 256];
    float4 b0 = bv[tid], b1 = bv[tid + 256];
    u16* orow = out + (size_t)row * D_;
    ushort4 o0, o1;
    o0.x = f2bf((a.x - mu) * rstd * g0.x + b0.x);
    o0.y = f2bf((a.y - mu) * rstd * g0.y + b0.y);
    o0.z = f2bf((a.z - mu) * rstd * g0.z + b0.z);
    o0.w = f2bf((a.w - mu) * rstd * g0.w + b0.w);
    o1.x = f2bf((c.x - mu) * rstd * g1.x + b1.x);
    o1.y = f2bf((c.y - mu) * rstd * g1.y + b1.y);
    o1.z = f2bf((c.z - mu) * rstd * g1.z + b1.z);
    o1.w = f2bf((c.w - mu) * rstd * g1.w + b1.w);
    *(ushort4*)&orow[tid * 4]         = o0;
    *(ushort4*)&orow[(tid + 256) * 4] = o1;
}

// ----------------------------------------------- transpose + fp32->bf16 cast
__global__ __launch_bounds__(256)
void tcvt_kernel(const float* __restrict__ W, u16* __restrict__ WT, int K, int N)
{
    __shared__ float t[32][33];
    int n0 = blockIdx.x << 5, k0 = blockIdx.y << 5;
    int tx = threadIdx.x & 31, ty = threadIdx.x >> 5;
    #pragma unroll
    for (int i = 0; i < 32; i += 8)
        t[ty + i][tx] = W[(size_t)(k0 + ty + i) * N + n0 + tx];
    __syncthreads();
    #pragma unroll
    for (int i = 0; i < 32; i += 8)
        WT[(size_t)(n0 + ty + i) * K + k0 + tx] = f2bf(t[tx][ty + i]);
}

// ---------------------------------------------------------------- GEMM bf16
// C[M,N] = A[M,K](bf16,row) * BT[N,K](bf16,row)^T + bias
// 128x256 tile, BK=64, 8 waves (2Mx4N). Triple-buffered K-tiles (144 KB LDS),
// 2 phases/K-tile, 16 MFMA/phase between raw s_barriers, counted vmcnt(6).
// Fragment loads are inline-asm ds_read_b128 so the compiler cannot insert
// its LDS-DMA alias-drain vmcnt(0) before them; lgkmcnt(0)+sched_barrier(0)
// provide the ordering we need (rule #18).
template<int EPI>
__global__ __launch_bounds__(512, 2)
void gemm_kernel(const u16* __restrict__ A, const u16* __restrict__ BT,
                 const float* __restrict__ bias, const float* __restrict__ res,
                 void* __restrict__ outv, int M, int N, int K)
{
    __shared__ u16 ldsA[3 * 8192];   // 3 bufs x 2 kslices x (128 x 32) = 48 KB
    __shared__ u16 ldsB[3 * 16384];  // 3 bufs x 2 kslices x (256 x 32) = 96 KB
    (void)M;

    int tid = threadIdx.x;
    int wid = tid >> 6, lane = tid & 63;
    int wm = wid >> 2, wn = wid & 3;          // 2 x 4 wave grid
    int quad = lane >> 4, l16 = lane & 15;

    // XCD-aware bijective swizzle (all grids % 8 == 0), N-major tile order.
    int nwg = (int)gridDim.x;
    int swz = ((int)blockIdx.x & 7) * (nwg >> 3) + ((int)blockIdx.x >> 3);
    int mt = swz & 31;                        // M/128 == 32 for all GEMMs here
    int nt = swz >> 5;
    int m0 = mt << 7, n0 = nt << 8;

    // staging decode: phys slot P = tid -> logical (row, 8-elem chunk), XOR swz
    int lo3 = (tid & 7) ^ ((tid >> 3) & 7);
    int rS  = ((tid >> 3) << 1) | (lo3 >> 2);
    int cS  = (lo3 & 3) << 3;
    const u16* gA  = A  + (size_t)(m0 + rS) * K + cS;
    const u16* gB0 = BT + (size_t)(n0 + rS) * K + cS;
    const u16* gB1 = gB0 + (size_t)128 * K;

    // fragment-read lane offset (u16 units): row=R0+l16, chunk=quad
    int slot   = (((l16 & 1) << 2) | quad) ^ (l16 >> 1);
    int laneRd = (l16 >> 1) * 64 + slot * 8;
    int aRd = wm * 2048 + laneRd;             // wave A rows: wm*64
    int bRd = wn * 2048 + laneRd;             // wave B cols: wn*64

    f32x4 acc[4][4] = {};

    auto stA = [&](int b, int ks, int kofs) {
        gld16(ldsA + b * 8192 + ks * 4096 + wid * 512, gA + kofs);
    };
    auto stB = [&](int b, int ks, int kofs) {
        gld16(ldsB + b * 16384 + ks * 8192 + wid * 512, gB0 + kofs);
        gld16(ldsB + b * 16384 + ks * 8192 + 4096 + wid * 512, gB1 + kofs);
    };
    // one phase = one k-step: 3 gld16, 8 asm ds_read_b128, 16 indep MFMA
    auto phase = [&](int bt, int ks, int stg, int kofs, bool vm) {
        stA(stg, ks, kofs);
        stB(stg, ks, kofs);
        const u16* ap = ldsA + bt * 8192 + ks * 4096 + aRd;
        const u16* bp = ldsB + bt * 16384 + ks * 8192 + bRd;
        bf16x8 af0 = dsr16(ap);
        bf16x8 af1 = dsr16(ap + 512);
        bf16x8 af2 = dsr16(ap + 1024);
        bf16x8 af3 = dsr16(ap + 1536);
        bf16x8 bf0 = dsr16(bp);
        bf16x8 bf1 = dsr16(bp + 512);
        bf16x8 bf2 = dsr16(bp + 1024);
        bf16x8 bf3 = dsr16(bp + 1536);
        __builtin_amdgcn_s_barrier();
        asm volatile("s_waitcnt lgkmcnt(0)" ::: "memory");
        __builtin_amdgcn_sched_barrier(0);
        __builtin_amdgcn_s_setprio(1);
        acc[0][0] = __builtin_amdgcn_mfma_f32_16x16x32_bf16(af0, bf0, acc[0][0], 0, 0, 0);
        acc[0][1] = __builtin_amdgcn_mfma_f32_16x16x32_bf16(af0, bf1, acc[0][1], 0, 0, 0);
        acc[0][2] = __builtin_amdgcn_mfma_f32_16x16x32_bf16(af0, bf2, acc[0][2], 0, 0, 0);
        acc[0][3] = __builtin_amdgcn_mfma_f32_16x16x32_bf16(af0, bf3, acc[0][3], 0, 0, 0);
        acc[1][0] = __builtin_amdgcn_mfma_f32_16x16x32_bf16(af1, bf0, acc[1][0], 0, 0, 0);
        acc[1][1] = __builtin_amdgcn_mfma_f32_16x16x32_bf16(af1, bf1, acc[1][1], 0, 0, 0);
        acc[1][2] = __builtin_amdgcn_mfma_f32_16x16x32_bf16(af1, bf2, acc[1][2], 0, 0, 0);
        acc[1][3] = __builtin_amdgcn_mfma_f32_16x16x32_bf16(af1, bf3, acc[1][3], 0, 0, 0);
        acc[2][0] = __builtin_amdgcn_mfma_f32_16x16x32_bf16(af2, bf0, acc[2][0], 0, 0, 0);
        acc[2][1] = __builtin_amdgcn_mfma_f32_16x16x32_bf16(af2, bf1, acc[2][1], 0, 0, 0);
        acc[2][2] = __builtin_amdgcn_mfma_f32_16x16x32_bf16(af2, bf2, acc[2][2], 0, 0, 0);
        acc[2][3] = __builtin_amdgcn_mfma_f32_16x16x32_bf16(af2, bf3, acc[2][3], 0, 0, 0);
        acc[3][0] = __builtin_amdgcn_mfma_f32_16x16x32_bf16(af3, bf0, acc[3][0], 0, 0, 0);
        acc[3][1] = __builtin_amdgcn_mfma_f32_16x16x32_bf16(af3, bf1, acc[3][1], 0, 0, 0);
        acc[3][2] = __builtin_amdgcn_mfma_f32_16x16x32_bf16(af3, bf2, acc[3][2], 0, 0, 0);
        acc[3][3] = __builtin_amdgcn_mfma_f32_16x16x32_bf16(af3, bf3, acc[3][3], 0, 0, 0);
        __builtin_amdgcn_sched_barrier(0);
        __builtin_amdgcn_s_setprio(0);
        if (vm) asm volatile("s_waitcnt vmcnt(6)" ::: "memory");
        __builtin_amdgcn_s_barrier();
    };

    int nkt = K >> 6;
    // prologue: stage T0, T1 fully; T0 landed (T1's 6 may stay in flight)
    stA(0, 0, 0);  stB(0, 0, 0);
    stA(0, 1, 32); stB(0, 1, 32);
    stA(1, 0, 64); stB(1, 0, 64);
    stA(1, 1, 96); stB(1, 1, 96);
    asm volatile("s_waitcnt vmcnt(6)" ::: "memory");
    __builtin_amdgcn_s_barrier();

    int cur = 0;
    for (int t = 0; t < nkt; ++t) {
        int stg = cur - 1; if (stg < 0) stg = 2;       // (cur + 2) % 3
        int tp = t + 2; if (tp > nkt - 1) tp = nkt - 1; // clamped (dead slot)
        int kofs = tp << 6;
        phase(cur, 0, stg, kofs,      false);
        phase(cur, 1, stg, kofs + 32, true);   // vmcnt(6): T(t+1) landed
        cur = cur + 1; if (cur > 2) cur = 0;
    }
    asm volatile("s_waitcnt vmcnt(0)" ::: "memory"); // drain LDS-DMA pre-endpgm

    u16*   outb = (u16*)outv;
    float* outf = (float*)outv;
    int colb = n0 + wn * 64, rowb = m0 + wm * 64;
    #pragma unroll
    for (int j = 0; j < 4; j++) {
        int col = colb + j * 16 + l16;
        float bv = bias[col];
        #pragma unroll
        for (int i = 0; i < 4; i++) {
            int row0 = rowb + i * 16 + (quad << 2);
            #pragma unroll
            for (int r = 0; r < 4; r++) {
                float v = acc[i][j][r] + bv;
                size_t idx = (size_t)(row0 + r) * N + col;
                if (EPI == 2) {
                    outf[idx] = v + res[idx];
                } else {
                    if (EPI == 1) v = 0.5f * v * (1.0f + erff(v * 0.70710678118654752f));
                    outb[idx] = f2bf(v);
                }
            }
        }
    }
}

// ---------------------------------------------------------- flash attention
__global__ __launch_bounds__(256, 2)
void attn_kernel(const u16* __restrict__ qkv, u16* __restrict__ av)
{
    __shared__ u16 ldsK[4][64][32];          // 16 KB  [d-chunk][key][32]
    __shared__ unsigned ldsVT[128][36];      // 18 KB  [d][key-pair]
    __shared__ u16 ldsP[4][32][72];          // 18 KB  per-wave P (2 sets)
    int tid = threadIdx.x, wid = tid >> 6, lane = tid & 63;
    int quad = lane >> 4, l16 = lane & 15;
    int bh = blockIdx.y, b = bh >> 4, h = bh & 15;
    int qx = gridDim.x - 1 - blockIdx.x;     // heavy causal blocks first
    int q0 = qx << 7;
    const u16* base = qkv + (size_t)b * S_ * (3 * D_);

    bf16x8 aq[2][4];
    #pragma unroll
    for (int set = 0; set < 2; set++) {
        int qrow = q0 + set * 64 + wid * 16 + l16;
        const u16* qp = base + (size_t)qrow * (3 * D_) + h * HD_;
        #pragma unroll
        for (int kk = 0; kk < 4; kk++)
            aq[set][kk] = *(const bf16x8*)(qp + kk * 32 + quad * 8);
    }

    float m_i[2][4], l_i[2][4];
    f32x4 oacc[2][8] = {};
    #pragma unroll
    for (int s = 0; s < 2; s++)
        #pragma unroll
        for (int r = 0; r < 4; r++) { m_i[s][r] = -1e30f; l_i[s][r] = 0.f; }

    const float scale = 0.088388347648318447f;  // 1/sqrt(128)
    int ntile = 2 * qx + 2;
    for (int jt = 0; jt < ntile; jt++) {
        int j0 = jt << 6;
        #pragma unroll
        for (int j = 0; j < 4; j++) {
            int c = wid * 4 + j;
            int kk = c >> 2, kb = c & 3;
            int key = (kb << 4) + (lane >> 2);
            const u16* g = base + (size_t)(j0 + key) * (3 * D_) + D_ + h * HD_
                         + kk * 32 + ((lane & 3) << 3);
            gld16((u16*)ldsK + c * 512, g);
        }
        {
            int kp = lane & 31, dhalf = lane >> 5;
            #pragma unroll
            for (int p = 0; p < 2; p++) {
                int doff = wid * 32 + p * 16 + dhalf * 8;
                const u16* g0 = base + (size_t)(j0 + 2 * kp) * (3 * D_)
                              + 2 * D_ + h * HD_ + doff;
                u16x8 v0 = *(const u16x8*)g0;
                u16x8 v1 = *(const u16x8*)(g0 + 3 * D_);
                #pragma unroll
                for (int k = 0; k < 8; k++)
                    ldsVT[doff + k][kp] = (unsigned)v0[k] | ((unsigned)v1[k] << 16);
            }
        }
        __syncthreads();
        f32x4 sacc[2][4] = {};
        #pragma unroll
        for (int kk = 0; kk < 4; kk++)
            #pragma unroll
            for (int n = 0; n < 4; n++) {
                bf16x8 bfr = *(const bf16x8*)&ldsK[kk][(n << 4) + l16][quad << 3];
                sacc[0][n] = __builtin_amdgcn_mfma_f32_16x16x32_bf16(aq[0][kk], bfr, sacc[0][n], 0, 0, 0);
                sacc[1][n] = __builtin_amdgcn_mfma_f32_16x16x32_bf16(aq[1][kk], bfr, sacc[1][n], 0, 0, 0);
            }
        #pragma unroll
        for (int set = 0; set < 2; set++) {
            float rowmax[4] = {-1e30f, -1e30f, -1e30f, -1e30f};
            #pragma unroll
            for (int n = 0; n < 4; n++) {
                int key = j0 + (n << 4) + l16;
                #pragma unroll
                for (int r = 0; r < 4; r++) {
                    float xv = sacc[set][n][r] * scale;
                    int qr = q0 + set * 64 + wid * 16 + (quad << 2) + r;
                    if (key > qr) xv = -1e30f;
                    sacc[set][n][r] = xv;
                    rowmax[r] = fmaxf(rowmax[r], xv);
                }
            }
            #pragma unroll
            for (int off = 1; off < 16; off <<= 1)
                #pragma unroll
                for (int r = 0; r < 4; r++)
                    rowmax[r] = fmaxf(rowmax[r], __shfl_xor(rowmax[r], off, 64));
            float alpha[4], rsum[4];
            #pragma unroll
            for (int r = 0; r < 4; r++) {
                float mn = fmaxf(m_i[set][r], rowmax[r]);
                alpha[r] = __expf(m_i[set][r] - mn);
                m_i[set][r] = mn;
                rsum[r] = 0.f;
            }
            #pragma unroll
            for (int n = 0; n < 4; n++)
                #pragma unroll
                for (int r = 0; r < 4; r++) {
                    float p = __expf(sacc[set][n][r] - m_i[set][r]);
                    rsum[r] += p;
                    ldsP[wid][set * 16 + (quad << 2) + r][(n << 4) + l16] = f2bf(p);
                }
            #pragma unroll
            for (int off = 1; off < 16; off <<= 1)
                #pragma unroll
                for (int r = 0; r < 4; r++)
                    rsum[r] += __shfl_xor(rsum[r], off, 64);
            #pragma unroll
            for (int r = 0; r < 4; r++)
                l_i[set][r] = l_i[set][r] * alpha[r] + rsum[r];
            #pragma unroll
            for (int n = 0; n < 8; n++)
                #pragma unroll
                for (int r = 0; r < 4; r++)
                    oacc[set][n][r] *= alpha[r];
        }
        #pragma unroll
        for (int ks = 0; ks < 2; ks++) {
            bf16x8 pa0 = *(const bf16x8*)&ldsP[wid][l16]     [(ks << 5) + (quad << 3)];
            bf16x8 pa1 = *(const bf16x8*)&ldsP[wid][16 + l16][(ks << 5) + (quad << 3)];
            #pragma unroll
            for (int n = 0; n < 8; n++) {
                bf16x8 vb = *(const bf16x8*)&ldsVT[(n << 4) + l16][(ks << 4) + (quad << 2)];
                oacc[0][n] = __builtin_amdgcn_mfma_f32_16x16x32_bf16(pa0, vb, oacc[0][n], 0, 0, 0);
                oacc[1][n] = __builtin_amdgcn_mfma_f32_16x16x32_bf16(pa1, vb, oacc[1][n], 0, 0, 0);
            }
        }
        __syncthreads();
    }
    #pragma unroll
    for (int set = 0; set < 2; set++)
        #pragma unroll
        for (int r = 0; r < 4; r++) {
            float inv = 1.0f / l_i[set][r];
            int qr = q0 + set * 64 + wid * 16 + (quad << 2) + r;
            u16* op = av + (size_t)(b * S_ + qr) * D_ + h * HD_;
            #pragma unroll
            for (int n = 0; n < 8; n++)
                op[(n << 4) + l16] = f2bf(oacc[set][n][r] * inv);
        }
}

// ------------------------------------------------------------------- launch
extern "C" void kernel_launch(void* const* d_in, const int* in_sizes, int n_in,
                              void* d_out, int out_size, void* d_ws, size_t ws_size,
                              hipStream_t stream)
{
    const float* x     = (const float*)d_in[0];
    const float* ln1_g = (const float*)d_in[1];
    const float* ln1_b = (const float*)d_in[2];
    const float* qkv_w = (const float*)d_in[3];
    const float* qkv_b = (const float*)d_in[4];
    const float* out_w = (const float*)d_in[5];
    const float* out_b = (const float*)d_in[6];
    const float* ln2_g = (const float*)d_in[7];
    const float* ln2_b = (const float*)d_in[8];
    const float* w1    = (const float*)d_in[9];
    const float* b1    = (const float*)d_in[10];
    const float* w2    = (const float*)d_in[11];
    const float* b2    = (const float*)d_in[12];
    float* out = (float*)d_out;

    char* ws  = (char*)d_ws;
    u16* wT   = (u16*)ws;                        // 32 MiB: transposed bf16 weights
    u16* hbuf = (u16*)(ws + (32u << 20));        // 16 MiB: ln1-out / av / ln2-out
    u16* big  = (u16*)(ws + (48u << 20));        // 64 MiB: qkv, then ffn act
    u16* qkvb = big;
    u16* ffb  = big;

    dim3 blk(256);
    dim3 gblk(512);

    ln_kernel<<<dim3(B_ * S_), blk, 0, stream>>>(x, ln1_g, ln1_b, hbuf);
    tcvt_kernel<<<dim3(6144 / 32, 2048 / 32), blk, 0, stream>>>(qkv_w, wT, 2048, 6144);
    gemm_kernel<0><<<dim3((6144 / 256) * (4096 / 128)), gblk, 0, stream>>>(
        hbuf, wT, qkv_b, nullptr, (void*)qkvb, 4096, 6144, 2048);
    attn_kernel<<<dim3(S_ / 128, B_ * H_), blk, 0, stream>>>(qkvb, hbuf);
    tcvt_kernel<<<dim3(2048 / 32, 2048 / 32), blk, 0, stream>>>(out_w, wT, 2048, 2048);
    gemm_kernel<2><<<dim3((2048 / 256) * (4096 / 128)), gblk, 0, stream>>>(
        hbuf, wT, out_b, x, (void*)out, 4096, 2048, 2048);
    ln_kernel<<<dim3(B_ * S_), blk, 0, stream>>>(out, ln2_g, ln2_b, hbuf);
    tcvt_kernel<<<dim3(8192 / 32, 2048 / 32), blk, 0, stream>>>(w1, wT, 2048, 8192);
    gemm_kernel<1><<<dim3((8192 / 256) * (4096 / 128)), gblk, 0, stream>>>(
        hbuf, wT, b1, nullptr, (void*)ffb, 4096, 8192, 2048);
    tcvt_kernel<<<dim3(2048 / 32, 8192 / 32), blk, 0, stream>>>(w2, wT, 8192, 2048);
    gemm_kernel<2><<<dim3((2048 / 256) * (4096 / 128)), gblk, 0, stream>>>(
        ffb, wT, b2, out, (void*)out, 4096, 2048, 8192);
}